// Round 13
// baseline (347.088 us; speedup 1.0000x reference)
//
#include <hip/hip_runtime.h>
#include <hip/hip_bf16.h>
#include <math.h>

#define HID 256
typedef __attribute__((ext_vector_type(8))) short s16x8;
typedef __attribute__((ext_vector_type(8))) ushort u16x8;
typedef __attribute__((ext_vector_type(4))) float f32x4;

__device__ __forceinline__ ushort f2bf(float f){
    uint u = __float_as_uint(f);
    u += 0x7FFF + ((u>>16)&1);
    return (ushort)(u>>16);
}
__device__ __forceinline__ float bf2f(ushort b){
    return __uint_as_float(((uint)b)<<16);
}

// gelu tanh-approx, tanh via fast exp: tanh(u) = 1 - 2/(1+exp(2u))
__device__ __forceinline__ float gelu_tanh(float x){
    float u = 0.7978845608028654f*(x + 0.044715f*x*x*x);
    float t = 1.0f - 2.0f/(1.0f + __expf(2.0f*u));
    return 0.5f*x*(1.0f+t);
}

// merged: weight convert (blocks < CVTB) + degree count (rest)
#define CVTB 1664
__global__ void k_cvt_count(const float* __restrict__ Win, const float* __restrict__ Wc,
    ushort* __restrict__ wbin, ushort* __restrict__ wbc,
    const int* __restrict__ dst, int* __restrict__ cnt, int E){
    int b = blockIdx.x;
    if(b < CVTB){
        int i = b*256 + threadIdx.x;
        if(i < 32768){
            int k = i >> 8, n = i & 255;
            int kb = k>>5, hi=(k>>3)&3, ii=k&7;
            wbin[((kb*256+n)*4+hi)*8 + ii] = f2bf(Win[i]);
        }else{
            int j = i - 32768;
            int l = j >> 16;
            int k = (j>>8)&255, n = j&255;
            int kb = k>>5, hi=(k>>3)&3, ii=k&7;
            wbc[l*65536 + ((kb*256+n)*4+hi)*8 + ii] = f2bf(Wc[j]);
        }
    }else{
        int e = (b-CVTB)*256 + threadIdx.x;
        if(e<E) atomicAdd(&cnt[dst[e]], 1);
    }
}

__global__ __launch_bounds__(256) void k_scan1(const int* __restrict__ cnt,
    int* __restrict__ tsum, int* __restrict__ bsum, int N){
    __shared__ int sm[256];
    int t = threadIdx.x, b = blockIdx.x;
    int base = b*1024 + t*4;
    int c0=0,c1=0,c2=0,c3=0;
    if(base+3 < N){
        int4 c = *reinterpret_cast<const int4*>(&cnt[base]);
        c0=c.x; c1=c.y; c2=c.z; c3=c.w;
    }else{
        if(base  <N) c0=cnt[base];
        if(base+1<N) c1=cnt[base+1];
        if(base+2<N) c2=cnt[base+2];
        if(base+3<N) c3=cnt[base+3];
    }
    int s = c0+c1+c2+c3;
    sm[t]=s; __syncthreads();
    for(int off=1; off<256; off<<=1){
        int v = sm[t];
        int a = (t>=off)? sm[t-off] : 0;
        __syncthreads();
        sm[t] = v+a;
        __syncthreads();
    }
    tsum[b*256+t] = sm[t]-s;
    if(t==255) bsum[b] = sm[255];
}

// scan3: each block sums bsum[0..b-1] itself (B<=20), writes indptr/cursor/dinv
__global__ __launch_bounds__(256) void k_scan3(const int* __restrict__ cnt,
    const int* __restrict__ tsum, const int* __restrict__ bsum,
    int* __restrict__ indptr, int* __restrict__ cursor, float* __restrict__ dinv,
    int N, int B){
    __shared__ int sboff;
    int t = threadIdx.x, b = blockIdx.x;
    if(t==0){
        int run=0, tot=0;
        for(int i=0;i<B;i++){ int v=bsum[i]; if(i<b) run+=v; tot+=v; }
        sboff=run;
        if(b==0) indptr[N]=tot;
    }
    __syncthreads();
    int base = b*1024 + t*4;
    int run = sboff + tsum[b*256+t];
    #pragma unroll
    for(int i=0;i<4;i++){
        int idx = base+i;
        if(idx<N){
            int c = cnt[idx];
            indptr[idx]=run; cursor[idx]=run;
            dinv[idx] = rsqrtf((float)(c+1));
            run += c;
        }
    }
}

__global__ void k_fill(const int* __restrict__ src, const int* __restrict__ dst,
    int* __restrict__ cursor, int* __restrict__ csr, int E){
    int e = blockIdx.x*blockDim.x + threadIdx.x;
    if(e<E){
        int pos = atomicAdd(&cursor[dst[e]], 1);
        csr[pos] = src[e];
    }
}

// pair-gather: 2 edges per wave-instruction (lane<32 / lane>=32 halves).
// yb[n] = bf16( dinv[n] * (dinv[n]*x[n] + sum_e dinv[src]*x[src]) )
__global__ __launch_bounds__(256) void k_agg(const ushort* __restrict__ xb,
    const int* __restrict__ indptr, const int* __restrict__ csr,
    const float* __restrict__ dinv, ushort* __restrict__ yb, int N)
{
    int wave = threadIdx.x>>6, lane = threadIdx.x&63;
    int n = blockIdx.x*4 + wave;
    if(n>=N) return;
    const u16x8* X8 = reinterpret_cast<const u16x8*>(xb);
    const int half = lane >> 5;
    const int l = lane & 31;
    float dn = dinv[n];
    float acc[8];
    {   // self loop: half 0 carries it with weight dn (outer dn applied at store)
        u16x8 v = X8[(size_t)n*32 + l];
        float w0 = (half==0)? dn : 0.f;
        #pragma unroll
        for(int j=0;j<8;j++) acc[j] = w0 * bf2f(v[j]);
    }
    int e0 = indptr[n], e1 = indptr[n+1];
    int e = e0;
    for(; e+8<=e1; e+=8){
        int is[4];
        #pragma unroll
        for(int q=0;q<4;q++) is[q] = csr[e + q*2 + half];
        u16x8 vs[4];
        #pragma unroll
        for(int q=0;q<4;q++) vs[q] = X8[(size_t)is[q]*32 + l];
        float ds[4];
        #pragma unroll
        for(int q=0;q<4;q++) ds[q] = dinv[is[q]];
        #pragma unroll
        for(int q=0;q<4;q++){
            #pragma unroll
            for(int j=0;j<8;j++) acc[j] = fmaf(ds[q], bf2f(vs[q][j]), acc[j]);
        }
    }
    for(; e+2<=e1; e+=2){
        int i = csr[e + half];
        u16x8 v = X8[(size_t)i*32 + l];
        float d = dinv[i];
        #pragma unroll
        for(int j=0;j<8;j++) acc[j] = fmaf(d, bf2f(v[j]), acc[j]);
    }
    if(e<e1){
        int i = csr[e];
        u16x8 v = X8[(size_t)i*32 + l];
        float d = (half==0)? dinv[i] : 0.f;
        #pragma unroll
        for(int j=0;j<8;j++) acc[j] = fmaf(d, bf2f(v[j]), acc[j]);
    }
    #pragma unroll
    for(int j=0;j<8;j++) acc[j] += __shfl_xor(acc[j], 32, 64);
    if(half==0){
        u16x8 o;
        #pragma unroll
        for(int j=0;j<8;j++) o[j] = f2bf(dn*acc[j]);
        reinterpret_cast<u16x8*>(yb)[(size_t)n*32 + l] = o;
    }
}

// R9-proven scalar epilogue, extended to 32-row tiles (2 groups of 4 waves).
// MODE: 0=INPUT (h0b=xb=o), 1=CONV (xb += 0.9o+0.1h0), 2=LAST (fout fp32)
template<int MODE>
__device__ __forceinline__ void epilogue32(f32x4 (&acc)[4],
    const float* __restrict__ bp, const float* __restrict__ gp, const float* __restrict__ bep,
    ushort* __restrict__ h0b, ushort* __restrict__ xb, float* __restrict__ fout,
    int row0, int g, int wc, int lr, int hi, int N,
    float (*sm1)[4], float (*sm2)[4])
{
    float bcv[4], gcv[4], bev[4];
    #pragma unroll
    for(int nf=0;nf<4;nf++){
        int col = wc*64 + nf*16 + lr;
        bcv[nf]=bp[col]; gcv[nf]=gp[col]; bev[nf]=bep[col];
    }
    #pragma unroll
    for(int r=0;r<4;r++){
        float ls1=0.f, ls2=0.f;
        #pragma unroll
        for(int nf=0;nf<4;nf++){
            float t = gelu_tanh(acc[nf][r] + bcv[nf]);
            acc[nf][r] = t;
            ls1 += t; ls2 += t*t;
        }
        #pragma unroll
        for(int off=1; off<16; off<<=1){
            ls1 += __shfl_xor(ls1, off, 64);
            ls2 += __shfl_xor(ls2, off, 64);
        }
        if(lr==0){
            int row = g*16 + hi*4 + r;
            sm1[row][wc]=ls1; sm2[row][wc]=ls2;
        }
    }
    __syncthreads();
    #pragma unroll
    for(int r=0;r<4;r++){
        int row = g*16 + hi*4 + r;
        int grow = row0 + row;
        if(grow >= N) continue;
        float S1 = sm1[row][0]+sm1[row][1]+sm1[row][2]+sm1[row][3];
        float S2 = sm2[row][0]+sm2[row][1]+sm2[row][2]+sm2[row][3];
        float mu = S1*(1.0f/256.0f);
        float var = fmaxf(S2*(1.0f/256.0f) - mu*mu, 0.0f);
        float rs = rsqrtf(var + 1e-5f);
        #pragma unroll
        for(int nf=0;nf<4;nf++){
            int col = wc*64 + nf*16 + lr;
            size_t idx = (size_t)grow*HID + col;
            float o = (acc[nf][r]-mu)*rs*gcv[nf] + bev[nf];
            if(MODE==0){
                ushort ob = f2bf(o);
                h0b[idx] = ob;
                xb[idx] = ob;
            }else{
                float xc = bf2f(xb[idx]) + 0.9f*o + 0.1f*bf2f(h0b[idx]);
                if(MODE==1) xb[idx] = f2bf(xc);
                else        fout[idx] = xc;
            }
        }
    }
}

// input block: 32-row tiles, 512 threads (2 groups x 4 col-waves), fp32 X direct
__global__ __launch_bounds__(512) void k_gemm_in(const float* __restrict__ X,
    const ushort* __restrict__ Wb,
    const float* __restrict__ bp, const float* __restrict__ gp, const float* __restrict__ bep,
    ushort* __restrict__ h0b, ushort* __restrict__ xb, int N)
{
    const int lane = threadIdx.x & 63;
    const int w = threadIdx.x >> 6;
    const int g = w >> 2;
    const int wc = w & 3;
    const int lr = lane & 15;
    const int hi = lane >> 4;
    const int row0 = blockIdx.x*32;
    __shared__ float sm1[32][4];
    __shared__ float sm2[32][4];

    f32x4 acc[4];
    #pragma unroll
    for(int n=0;n<4;n++){ acc[n].x=0.f; acc[n].y=0.f; acc[n].z=0.f; acc[n].w=0.f; }

    int r0 = row0 + g*16 + lr; if(r0 >= N) r0 = N-1;
    const float* xp0 = X + (size_t)r0*128 + hi*8;
    const ushort* bpp = Wb + (wc*64 + lr)*32 + hi*8;

    #pragma unroll
    for(int kb=0; kb<4; kb++){
        float4 p0a = *reinterpret_cast<const float4*>(xp0 + kb*32);
        float4 p0b = *reinterpret_cast<const float4*>(xp0 + kb*32 + 4);
        s16x8 a0;
        a0[0]=(short)f2bf(p0a.x); a0[1]=(short)f2bf(p0a.y); a0[2]=(short)f2bf(p0a.z); a0[3]=(short)f2bf(p0a.w);
        a0[4]=(short)f2bf(p0b.x); a0[5]=(short)f2bf(p0b.y); a0[6]=(short)f2bf(p0b.z); a0[7]=(short)f2bf(p0b.w);
        #pragma unroll
        for(int nf=0;nf<4;nf++){
            s16x8 b = *reinterpret_cast<const s16x8*>(bpp + kb*8192 + nf*512);
            acc[nf] = __builtin_amdgcn_mfma_f32_16x16x32_bf16(a0, b, acc[nf], 0,0,0);
        }
    }
    epilogue32<0>(acc, bp, gp, bep, h0b, xb, nullptr, row0, g, wc, lr, hi, N, sm1, sm2);
}

// conv GEMM: 32-row tiles, 512 threads, A = yb (aggregated bf16), fused epilogue
template<int MODE>
__global__ __launch_bounds__(512) void k_gemm_fused(const ushort* __restrict__ A,
    const ushort* __restrict__ Wb,
    const float* __restrict__ bp, const float* __restrict__ gp, const float* __restrict__ bep,
    ushort* __restrict__ h0b, ushort* __restrict__ xb, float* __restrict__ fout, int N)
{
    const int lane = threadIdx.x & 63;
    const int w = threadIdx.x >> 6;
    const int g = w >> 2;
    const int wc = w & 3;
    const int lr = lane & 15;
    const int hi = lane >> 4;
    const int row0 = blockIdx.x*32;
    __shared__ float sm1[32][4];
    __shared__ float sm2[32][4];

    f32x4 acc[4];
    #pragma unroll
    for(int n=0;n<4;n++){ acc[n].x=0.f; acc[n].y=0.f; acc[n].z=0.f; acc[n].w=0.f; }

    int r0 = row0 + g*16 + lr; if(r0 >= N) r0 = N-1;
    const ushort* ap0 = A + (size_t)r0*256 + hi*8;
    const ushort* bpp = Wb + (wc*64 + lr)*32 + hi*8;

    s16x8 a0[2], bb[2][4];
    a0[0] = *reinterpret_cast<const s16x8*>(ap0);
    #pragma unroll
    for(int nf=0;nf<4;nf++) bb[0][nf] = *reinterpret_cast<const s16x8*>(bpp + nf*512);

    #pragma unroll
    for(int kb=0; kb<8; kb++){
        const int cur = kb&1, nxt = cur^1;
        if(kb < 7){
            a0[nxt] = *reinterpret_cast<const s16x8*>(ap0 + (kb+1)*32);
            #pragma unroll
            for(int nf=0;nf<4;nf++)
                bb[nxt][nf] = *reinterpret_cast<const s16x8*>(bpp + (kb+1)*8192 + nf*512);
        }
        #pragma unroll
        for(int nf=0;nf<4;nf++)
            acc[nf] = __builtin_amdgcn_mfma_f32_16x16x32_bf16(a0[cur], bb[cur][nf], acc[nf], 0,0,0);
    }
    epilogue32<MODE>(acc, bp, gp, bep, h0b, xb, fout, row0, g, wc, lr, hi, N, sm1, sm2);
}

extern "C" void kernel_launch(void* const* d_in, const int* in_sizes, int n_in,
                              void* d_out, int out_size, void* d_ws, size_t ws_size,
                              hipStream_t stream){
    const float* x     = (const float*)d_in[0];
    const int*   ei    = (const int*)d_in[1];
    const float* W_in  = (const float*)d_in[2];
    const float* b_in  = (const float*)d_in[3];
    const float* g_in  = (const float*)d_in[4];
    const float* be_in = (const float*)d_in[5];
    const float* Wc    = (const float*)d_in[6];
    const float* bc    = (const float*)d_in[7];
    const float* gc    = (const float*)d_in[8];
    const float* bec   = (const float*)d_in[9];
    const int N = in_sizes[0]/128;
    const int E = in_sizes[1]/2;
    const int* src = ei;
    const int* dst = ei + E;
    float* fout = (float*)d_out;
    const int B = (N+1023)/1024;

    char* w = (char*)d_ws;
    ushort* xb   = (ushort*)w; w += (size_t)N*HID*2;
    ushort* yb   = (ushort*)w; w += (size_t)N*HID*2;
    ushort* h0b  = (ushort*)w; w += (size_t)N*HID*2;
    ushort* wbin = (ushort*)w; w += (size_t)128*256*2;
    ushort* wbc  = (ushort*)w; w += (size_t)6*65536*2;
    float* dinv  = (float*)w;  w += (size_t)N*4;
    int* cnt     = (int*)w;    w += (size_t)N*4;
    int* cursor  = (int*)w;    w += (size_t)N*4;
    int* csr     = (int*)w;    w += (size_t)E*4;
    int* indptr  = (int*)w;    w += (size_t)(N+1)*4;
    int* tsum    = (int*)w;    w += (size_t)B*256*4;
    int* bsum    = (int*)w;    w += (size_t)B*4;

    (void)hipMemsetAsync(cnt, 0, (size_t)N*4, stream);
    k_cvt_count<<<CVTB + (E+255)/256,256,0,stream>>>(W_in, Wc, wbin, wbc, dst, cnt, E);
    k_scan1<<<B,256,0,stream>>>(cnt, tsum, bsum, N);
    k_scan3<<<B,256,0,stream>>>(cnt, tsum, bsum, indptr, cursor, dinv, N, B);
    k_fill<<<(E+255)/256,256,0,stream>>>(src,dst,cursor,csr,E);

    const int GB = (N+31)/32;
    k_gemm_in<<<GB,512,0,stream>>>(x, wbin, b_in, g_in, be_in, h0b, xb, N);
    for(int l=0;l<6;l++){
        k_agg<<<(N+3)/4,256,0,stream>>>(xb, indptr, csr, dinv, yb, N);
        if(l<5)
            k_gemm_fused<1><<<GB,512,0,stream>>>(yb, wbc+(size_t)l*65536,
                bc+(size_t)l*HID, gc+(size_t)l*HID, bec+(size_t)l*HID,
                h0b, xb, nullptr, N);
        else
            k_gemm_fused<2><<<GB,512,0,stream>>>(yb, wbc+(size_t)l*65536,
                bc+(size_t)l*HID, gc+(size_t)l*HID, bec+(size_t)l*HID,
                h0b, xb, fout, N);
    }
}

// Round 14
// 328.854 us; speedup vs baseline: 1.0554x; 1.0554x over previous
//
#include <hip/hip_runtime.h>
#include <hip/hip_bf16.h>
#include <math.h>

#define HID 256
typedef __attribute__((ext_vector_type(8))) short s16x8;
typedef __attribute__((ext_vector_type(8))) ushort u16x8;
typedef __attribute__((ext_vector_type(4))) float f32x4;

__device__ __forceinline__ ushort f2bf(float f){
    uint u = __float_as_uint(f);
    u += 0x7FFF + ((u>>16)&1);
    return (ushort)(u>>16);
}
__device__ __forceinline__ float bf2f(ushort b){
    return __uint_as_float(((uint)b)<<16);
}

// gelu tanh-approx, tanh via fast exp: tanh(u) = 1 - 2/(1+exp(2u))
__device__ __forceinline__ float gelu_tanh(float x){
    float u = 0.7978845608028654f*(x + 0.044715f*x*x*x);
    float t = 1.0f - 2.0f/(1.0f + __expf(2.0f*u));
    return 0.5f*x*(1.0f+t);
}

// merged: weight convert (blocks < CVTB) + degree count (rest)
#define CVTB 1664
__global__ void k_cvt_count(const float* __restrict__ Win, const float* __restrict__ Wc,
    ushort* __restrict__ wbin, ushort* __restrict__ wbc,
    const int* __restrict__ dst, int* __restrict__ cnt, int E){
    int b = blockIdx.x;
    if(b < CVTB){
        int i = b*256 + threadIdx.x;
        if(i < 32768){
            int k = i >> 8, n = i & 255;
            int kb = k>>5, hi=(k>>3)&3, ii=k&7;
            wbin[((kb*256+n)*4+hi)*8 + ii] = f2bf(Win[i]);
        }else{
            int j = i - 32768;
            int l = j >> 16;
            int k = (j>>8)&255, n = j&255;
            int kb = k>>5, hi=(k>>3)&3, ii=k&7;
            wbc[l*65536 + ((kb*256+n)*4+hi)*8 + ii] = f2bf(Wc[j]);
        }
    }else{
        int e = (b-CVTB)*256 + threadIdx.x;
        if(e<E) atomicAdd(&cnt[dst[e]], 1);
    }
}

__global__ __launch_bounds__(256) void k_scan1(const int* __restrict__ cnt,
    int* __restrict__ tsum, int* __restrict__ bsum, int N){
    __shared__ int sm[256];
    int t = threadIdx.x, b = blockIdx.x;
    int base = b*1024 + t*4;
    int c0=0,c1=0,c2=0,c3=0;
    if(base+3 < N){
        int4 c = *reinterpret_cast<const int4*>(&cnt[base]);
        c0=c.x; c1=c.y; c2=c.z; c3=c.w;
    }else{
        if(base  <N) c0=cnt[base];
        if(base+1<N) c1=cnt[base+1];
        if(base+2<N) c2=cnt[base+2];
        if(base+3<N) c3=cnt[base+3];
    }
    int s = c0+c1+c2+c3;
    sm[t]=s; __syncthreads();
    for(int off=1; off<256; off<<=1){
        int v = sm[t];
        int a = (t>=off)? sm[t-off] : 0;
        __syncthreads();
        sm[t] = v+a;
        __syncthreads();
    }
    tsum[b*256+t] = sm[t]-s;
    if(t==255) bsum[b] = sm[255];
}

// scan3: each block sums bsum[0..b-1] itself (B<=20), writes indptr/cursor/dinv
__global__ __launch_bounds__(256) void k_scan3(const int* __restrict__ cnt,
    const int* __restrict__ tsum, const int* __restrict__ bsum,
    int* __restrict__ indptr, int* __restrict__ cursor, float* __restrict__ dinv,
    int N, int B){
    __shared__ int sboff;
    int t = threadIdx.x, b = blockIdx.x;
    if(t==0){
        int run=0, tot=0;
        for(int i=0;i<B;i++){ int v=bsum[i]; if(i<b) run+=v; tot+=v; }
        sboff=run;
        if(b==0) indptr[N]=tot;
    }
    __syncthreads();
    int base = b*1024 + t*4;
    int run = sboff + tsum[b*256+t];
    #pragma unroll
    for(int i=0;i<4;i++){
        int idx = base+i;
        if(idx<N){
            int c = cnt[idx];
            indptr[idx]=run; cursor[idx]=run;
            dinv[idx] = rsqrtf((float)(c+1));
            run += c;
        }
    }
}

// fill: pack (src, dinv[src]) per edge so k_agg needs one 8B load per edge
__global__ void k_fill(const int* __restrict__ src, const int* __restrict__ dst,
    int* __restrict__ cursor, const float* __restrict__ dinv,
    int2* __restrict__ csr2, int E){
    int e = blockIdx.x*blockDim.x + threadIdx.x;
    if(e<E){
        int s = src[e];
        int pos = atomicAdd(&cursor[dst[e]], 1);
        csr2[pos] = make_int2(s, __float_as_int(dinv[s]));
    }
}

// pair-gather: 2 edges per wave-instruction (lane<32 / lane>=32 halves).
// csr2 packs (src, dinv[src]) -> 2 VMEM instrs per edge instead of 3.
// yb[n] = bf16( dinv[n] * (dinv[n]*x[n] + sum_e dinv[src]*x[src]) )
__global__ __launch_bounds__(256) void k_agg(const ushort* __restrict__ xb,
    const int* __restrict__ indptr, const int2* __restrict__ csr2,
    const float* __restrict__ dinv, ushort* __restrict__ yb, int N)
{
    int wave = threadIdx.x>>6, lane = threadIdx.x&63;
    int n = blockIdx.x*4 + wave;
    if(n>=N) return;
    const u16x8* X8 = reinterpret_cast<const u16x8*>(xb);
    const int half = lane >> 5;
    const int l = lane & 31;
    float dn = dinv[n];
    float acc[8];
    {   // self loop: half 0 carries it with weight dn (outer dn applied at store)
        u16x8 v = X8[(size_t)n*32 + l];
        float w0 = (half==0)? dn : 0.f;
        #pragma unroll
        for(int j=0;j<8;j++) acc[j] = w0 * bf2f(v[j]);
    }
    int e0 = indptr[n], e1 = indptr[n+1];
    int e = e0;
    for(; e+8<=e1; e+=8){
        int2 p[4];
        #pragma unroll
        for(int q=0;q<4;q++) p[q] = csr2[e + q*2 + half];
        u16x8 vs[4];
        #pragma unroll
        for(int q=0;q<4;q++) vs[q] = X8[(size_t)p[q].x*32 + l];
        #pragma unroll
        for(int q=0;q<4;q++){
            float d = __int_as_float(p[q].y);
            #pragma unroll
            for(int j=0;j<8;j++) acc[j] = fmaf(d, bf2f(vs[q][j]), acc[j]);
        }
    }
    for(; e+2<=e1; e+=2){
        int2 p = csr2[e + half];
        u16x8 v = X8[(size_t)p.x*32 + l];
        float d = __int_as_float(p.y);
        #pragma unroll
        for(int j=0;j<8;j++) acc[j] = fmaf(d, bf2f(v[j]), acc[j]);
    }
    if(e<e1){
        int2 p = csr2[e];
        u16x8 v = X8[(size_t)p.x*32 + l];
        float d = (half==0)? __int_as_float(p.y) : 0.f;
        #pragma unroll
        for(int j=0;j<8;j++) acc[j] = fmaf(d, bf2f(v[j]), acc[j]);
    }
    #pragma unroll
    for(int j=0;j<8;j++) acc[j] += __shfl_xor(acc[j], 32, 64);
    if(half==0){
        u16x8 o;
        #pragma unroll
        for(int j=0;j<8;j++) o[j] = f2bf(dn*acc[j]);
        reinterpret_cast<u16x8*>(yb)[(size_t)n*32 + l] = o;
    }
}

// epilogue for 16-row tiles. MODE: 0=INPUT (h0b=xb=o), 1=CONV (xb += 0.9o+0.1h0),
// 2=LAST (fout = xb + 0.9o + 0.1h0, fp32)
template<int MODE>
__device__ __forceinline__ void epilogue16(f32x4 (&acc)[4],
    const float* __restrict__ bp, const float* __restrict__ gp, const float* __restrict__ bep,
    ushort* __restrict__ h0b, ushort* __restrict__ xb, float* __restrict__ fout,
    int row0, int wc, int lr, int hi, int N,
    float (*sm1)[4], float (*sm2)[4])
{
    float bcv[4], gcv[4], bev[4];
    #pragma unroll
    for(int nf=0;nf<4;nf++){
        int col = wc*64 + nf*16 + lr;
        bcv[nf]=bp[col]; gcv[nf]=gp[col]; bev[nf]=bep[col];
    }
    #pragma unroll
    for(int r=0;r<4;r++){
        float ls1=0.f, ls2=0.f;
        #pragma unroll
        for(int nf=0;nf<4;nf++){
            float t = gelu_tanh(acc[nf][r] + bcv[nf]);
            acc[nf][r] = t;
            ls1 += t; ls2 += t*t;
        }
        #pragma unroll
        for(int off=1; off<16; off<<=1){
            ls1 += __shfl_xor(ls1, off, 64);
            ls2 += __shfl_xor(ls2, off, 64);
        }
        if(lr==0){
            int row = hi*4 + r;
            sm1[row][wc]=ls1; sm2[row][wc]=ls2;
        }
    }
    __syncthreads();
    #pragma unroll
    for(int r=0;r<4;r++){
        int row = hi*4 + r;
        int grow = row0 + row;
        if(grow >= N) continue;
        float S1 = sm1[row][0]+sm1[row][1]+sm1[row][2]+sm1[row][3];
        float S2 = sm2[row][0]+sm2[row][1]+sm2[row][2]+sm2[row][3];
        float mu = S1*(1.0f/256.0f);
        float var = fmaxf(S2*(1.0f/256.0f) - mu*mu, 0.0f);
        float rs = rsqrtf(var + 1e-5f);
        #pragma unroll
        for(int nf=0;nf<4;nf++){
            int col = wc*64 + nf*16 + lr;
            size_t idx = (size_t)grow*HID + col;
            float o = (acc[nf][r]-mu)*rs*gcv[nf] + bev[nf];
            if(MODE==0){
                ushort ob = f2bf(o);
                h0b[idx] = ob;
                xb[idx] = ob;
            }else{
                float xc = bf2f(xb[idx]) + 0.9f*o + 0.1f*bf2f(h0b[idx]);
                if(MODE==1) xb[idx] = f2bf(xc);
                else        fout[idx] = xc;
            }
        }
    }
}

// input block: 16-row tiles, reads fp32 X[N][128] directly, converts fragments in-reg
__global__ __launch_bounds__(256) void k_gemm_in(const float* __restrict__ X,
    const ushort* __restrict__ Wb,
    const float* __restrict__ bp, const float* __restrict__ gp, const float* __restrict__ bep,
    ushort* __restrict__ h0b, ushort* __restrict__ xb, int N)
{
    const int lane = threadIdx.x & 63;
    const int wc = threadIdx.x >> 6;
    const int lr = lane & 15;
    const int hi = lane >> 4;
    const int row0 = blockIdx.x*16;
    __shared__ float sm1[16][4];
    __shared__ float sm2[16][4];

    f32x4 acc[4];
    #pragma unroll
    for(int n=0;n<4;n++){ acc[n].x=0.f; acc[n].y=0.f; acc[n].z=0.f; acc[n].w=0.f; }

    int r0 = row0 + lr; if(r0 >= N) r0 = N-1;
    const float* xp0 = X + (size_t)r0*128 + hi*8;
    const ushort* bpp = Wb + (wc*64 + lr)*32 + hi*8;

    #pragma unroll
    for(int kb=0; kb<4; kb++){
        float4 p0a = *reinterpret_cast<const float4*>(xp0 + kb*32);
        float4 p0b = *reinterpret_cast<const float4*>(xp0 + kb*32 + 4);
        s16x8 a0;
        a0[0]=(short)f2bf(p0a.x); a0[1]=(short)f2bf(p0a.y); a0[2]=(short)f2bf(p0a.z); a0[3]=(short)f2bf(p0a.w);
        a0[4]=(short)f2bf(p0b.x); a0[5]=(short)f2bf(p0b.y); a0[6]=(short)f2bf(p0b.z); a0[7]=(short)f2bf(p0b.w);
        #pragma unroll
        for(int nf=0;nf<4;nf++){
            s16x8 b = *reinterpret_cast<const s16x8*>(bpp + kb*8192 + nf*512);
            acc[nf] = __builtin_amdgcn_mfma_f32_16x16x32_bf16(a0, b, acc[nf], 0,0,0);
        }
    }
    epilogue16<0>(acc, bp, gp, bep, h0b, xb, nullptr, row0, wc, lr, hi, N, sm1, sm2);
}

// conv GEMM: 16-row tiles, A = yb (aggregated bf16), fused bias/gelu/LN/blend
template<int MODE>
__global__ __launch_bounds__(256) void k_gemm_fused(const ushort* __restrict__ A,
    const ushort* __restrict__ Wb,
    const float* __restrict__ bp, const float* __restrict__ gp, const float* __restrict__ bep,
    ushort* __restrict__ h0b, ushort* __restrict__ xb, float* __restrict__ fout, int N)
{
    const int lane = threadIdx.x & 63;
    const int wc = threadIdx.x >> 6;
    const int lr = lane & 15;
    const int hi = lane >> 4;
    const int row0 = blockIdx.x*16;
    __shared__ float sm1[16][4];
    __shared__ float sm2[16][4];

    f32x4 acc[4];
    #pragma unroll
    for(int n=0;n<4;n++){ acc[n].x=0.f; acc[n].y=0.f; acc[n].z=0.f; acc[n].w=0.f; }

    int r0 = row0 + lr; if(r0 >= N) r0 = N-1;
    const ushort* ap0 = A + (size_t)r0*256 + hi*8;
    const ushort* bpp = Wb + (wc*64 + lr)*32 + hi*8;

    s16x8 a0[2], bb[2][4];
    a0[0] = *reinterpret_cast<const s16x8*>(ap0);
    #pragma unroll
    for(int nf=0;nf<4;nf++) bb[0][nf] = *reinterpret_cast<const s16x8*>(bpp + nf*512);

    #pragma unroll
    for(int kb=0; kb<8; kb++){
        const int cur = kb&1, nxt = cur^1;
        if(kb < 7){
            a0[nxt] = *reinterpret_cast<const s16x8*>(ap0 + (kb+1)*32);
            #pragma unroll
            for(int nf=0;nf<4;nf++)
                bb[nxt][nf] = *reinterpret_cast<const s16x8*>(bpp + (kb+1)*8192 + nf*512);
        }
        #pragma unroll
        for(int nf=0;nf<4;nf++)
            acc[nf] = __builtin_amdgcn_mfma_f32_16x16x32_bf16(a0[cur], bb[cur][nf], acc[nf], 0,0,0);
    }
    epilogue16<MODE>(acc, bp, gp, bep, h0b, xb, fout, row0, wc, lr, hi, N, sm1, sm2);
}

extern "C" void kernel_launch(void* const* d_in, const int* in_sizes, int n_in,
                              void* d_out, int out_size, void* d_ws, size_t ws_size,
                              hipStream_t stream){
    const float* x     = (const float*)d_in[0];
    const int*   ei    = (const int*)d_in[1];
    const float* W_in  = (const float*)d_in[2];
    const float* b_in  = (const float*)d_in[3];
    const float* g_in  = (const float*)d_in[4];
    const float* be_in = (const float*)d_in[5];
    const float* Wc    = (const float*)d_in[6];
    const float* bc    = (const float*)d_in[7];
    const float* gc    = (const float*)d_in[8];
    const float* bec   = (const float*)d_in[9];
    const int N = in_sizes[0]/128;
    const int E = in_sizes[1]/2;
    const int* src = ei;
    const int* dst = ei + E;
    float* fout = (float*)d_out;
    const int B = (N+1023)/1024;

    char* w = (char*)d_ws;
    ushort* xb   = (ushort*)w; w += (size_t)N*HID*2;
    ushort* yb   = (ushort*)w; w += (size_t)N*HID*2;
    ushort* h0b  = (ushort*)w; w += (size_t)N*HID*2;
    ushort* wbin = (ushort*)w; w += (size_t)128*256*2;
    ushort* wbc  = (ushort*)w; w += (size_t)6*65536*2;
    float* dinv  = (float*)w;  w += (size_t)N*4;
    int* cnt     = (int*)w;    w += (size_t)N*4;
    int* cursor  = (int*)w;    w += (size_t)N*4;
    int2* csr2   = (int2*)w;   w += (size_t)E*8;
    int* indptr  = (int*)w;    w += (size_t)(N+1)*4;
    int* tsum    = (int*)w;    w += (size_t)B*256*4;
    int* bsum    = (int*)w;    w += (size_t)B*4;

    (void)hipMemsetAsync(cnt, 0, (size_t)N*4, stream);
    k_cvt_count<<<CVTB + (E+255)/256,256,0,stream>>>(W_in, Wc, wbin, wbc, dst, cnt, E);
    k_scan1<<<B,256,0,stream>>>(cnt, tsum, bsum, N);
    k_scan3<<<B,256,0,stream>>>(cnt, tsum, bsum, indptr, cursor, dinv, N, B);
    k_fill<<<(E+255)/256,256,0,stream>>>(src, dst, cursor, dinv, csr2, E);

    const int GB = (N+15)/16;
    k_gemm_in<<<GB,256,0,stream>>>(x, wbin, b_in, g_in, be_in, h0b, xb, N);
    for(int l=0;l<6;l++){
        k_agg<<<(N+3)/4,256,0,stream>>>(xb, indptr, csr2, dinv, yb, N);
        if(l<5)
            k_gemm_fused<1><<<GB,256,0,stream>>>(yb, wbc+(size_t)l*65536,
                bc+(size_t)l*HID, gc+(size_t)l*HID, bec+(size_t)l*HID,
                h0b, xb, nullptr, N);
        else
            k_gemm_fused<2><<<GB,256,0,stream>>>(yb, wbc+(size_t)l*65536,
                bc+(size_t)l*HID, gc+(size_t)l*HID, bec+(size_t)l*HID,
                h0b, xb, fout, N);
    }
}

// Round 15
// 326.330 us; speedup vs baseline: 1.0636x; 1.0077x over previous
//
#include <hip/hip_runtime.h>
#include <hip/hip_bf16.h>
#include <math.h>

#define HID 256
typedef __attribute__((ext_vector_type(8))) short s16x8;
typedef __attribute__((ext_vector_type(8))) ushort u16x8;
typedef __attribute__((ext_vector_type(4))) float f32x4;

__device__ __forceinline__ ushort f2bf(float f){
    uint u = __float_as_uint(f);
    u += 0x7FFF + ((u>>16)&1);
    return (ushort)(u>>16);
}
__device__ __forceinline__ float bf2f(ushort b){
    return __uint_as_float(((uint)b)<<16);
}

// gelu tanh-approx, tanh via fast exp: tanh(u) = 1 - 2/(1+exp(2u))
__device__ __forceinline__ float gelu_tanh(float x){
    float u = 0.7978845608028654f*(x + 0.044715f*x*x*x);
    float t = 1.0f - 2.0f/(1.0f + __expf(2.0f*u));
    return 0.5f*x*(1.0f+t);
}

__global__ void k_zero(int* __restrict__ cnt, int N){
    int i = blockIdx.x*blockDim.x + threadIdx.x;
    if(i<N) cnt[i]=0;
}

// merged: weight convert (blocks < CVTB) + degree count (rest)
#define CVTB 1664
__global__ void k_cvt_count(const float* __restrict__ Win, const float* __restrict__ Wc,
    ushort* __restrict__ wbin, ushort* __restrict__ wbc,
    const int* __restrict__ dst, int* __restrict__ cnt, int E){
    int b = blockIdx.x;
    if(b < CVTB){
        int i = b*256 + threadIdx.x;
        if(i < 32768){
            int k = i >> 8, n = i & 255;
            int kb = k>>5, hi=(k>>3)&3, ii=k&7;
            wbin[((kb*256+n)*4+hi)*8 + ii] = f2bf(Win[i]);
        }else{
            int j = i - 32768;
            int l = j >> 16;
            int k = (j>>8)&255, n = j&255;
            int kb = k>>5, hi=(k>>3)&3, ii=k&7;
            wbc[l*65536 + ((kb*256+n)*4+hi)*8 + ii] = f2bf(Wc[j]);
        }
    }else{
        int e = (b-CVTB)*256 + threadIdx.x;
        if(e<E) atomicAdd(&cnt[dst[e]], 1);
    }
}

__global__ __launch_bounds__(256) void k_scan1(const int* __restrict__ cnt,
    int* __restrict__ tsum, int* __restrict__ bsum, int N){
    __shared__ int sm[256];
    int t = threadIdx.x, b = blockIdx.x;
    int base = b*1024 + t*4;
    int c0=0,c1=0,c2=0,c3=0;
    if(base+3 < N){
        int4 c = *reinterpret_cast<const int4*>(&cnt[base]);
        c0=c.x; c1=c.y; c2=c.z; c3=c.w;
    }else{
        if(base  <N) c0=cnt[base];
        if(base+1<N) c1=cnt[base+1];
        if(base+2<N) c2=cnt[base+2];
        if(base+3<N) c3=cnt[base+3];
    }
    int s = c0+c1+c2+c3;
    sm[t]=s; __syncthreads();
    for(int off=1; off<256; off<<=1){
        int v = sm[t];
        int a = (t>=off)? sm[t-off] : 0;
        __syncthreads();
        sm[t] = v+a;
        __syncthreads();
    }
    tsum[b*256+t] = sm[t]-s;
    if(t==255) bsum[b] = sm[255];
}

// scan3: each block sums bsum[0..b-1] itself (B<=20), writes indptr/cursor/dinv
__global__ __launch_bounds__(256) void k_scan3(const int* __restrict__ cnt,
    const int* __restrict__ tsum, const int* __restrict__ bsum,
    int* __restrict__ indptr, int* __restrict__ cursor, float* __restrict__ dinv,
    int N, int B){
    __shared__ int sboff;
    int t = threadIdx.x, b = blockIdx.x;
    if(t==0){
        int run=0, tot=0;
        for(int i=0;i<B;i++){ int v=bsum[i]; if(i<b) run+=v; tot+=v; }
        sboff=run;
        if(b==0) indptr[N]=tot;
    }
    __syncthreads();
    int base = b*1024 + t*4;
    int run = sboff + tsum[b*256+t];
    #pragma unroll
    for(int i=0;i<4;i++){
        int idx = base+i;
        if(idx<N){
            int c = cnt[idx];
            indptr[idx]=run; cursor[idx]=run;
            dinv[idx] = rsqrtf((float)(c+1));
            run += c;
        }
    }
}

__global__ void k_fill(const int* __restrict__ src, const int* __restrict__ dst,
    int* __restrict__ cursor, int* __restrict__ csr, int E){
    int e = blockIdx.x*blockDim.x + threadIdx.x;
    if(e<E){
        int pos = atomicAdd(&cursor[dst[e]], 1);
        csr[pos] = src[e];
    }
}

// pair-gather: 2 edges per wave-instruction (lane<32 / lane>=32 halves).
// yb[n] = bf16( dinv[n] * (dinv[n]*x[n] + sum_e dinv[src]*x[src]) )
__global__ __launch_bounds__(256) void k_agg(const ushort* __restrict__ xb,
    const int* __restrict__ indptr, const int* __restrict__ csr,
    const float* __restrict__ dinv, ushort* __restrict__ yb, int N)
{
    int wave = threadIdx.x>>6, lane = threadIdx.x&63;
    int n = blockIdx.x*4 + wave;
    if(n>=N) return;
    const u16x8* X8 = reinterpret_cast<const u16x8*>(xb);
    const int half = lane >> 5;
    const int l = lane & 31;
    float dn = dinv[n];
    float acc[8];
    {   // self loop: half 0 carries it with weight dn (outer dn applied at store)
        u16x8 v = X8[(size_t)n*32 + l];
        float w0 = (half==0)? dn : 0.f;
        #pragma unroll
        for(int j=0;j<8;j++) acc[j] = w0 * bf2f(v[j]);
    }
    int e0 = indptr[n], e1 = indptr[n+1];
    int e = e0;
    for(; e+8<=e1; e+=8){
        int is[4];
        #pragma unroll
        for(int q=0;q<4;q++) is[q] = csr[e + q*2 + half];
        u16x8 vs[4];
        #pragma unroll
        for(int q=0;q<4;q++) vs[q] = X8[(size_t)is[q]*32 + l];
        float ds[4];
        #pragma unroll
        for(int q=0;q<4;q++) ds[q] = dinv[is[q]];
        #pragma unroll
        for(int q=0;q<4;q++){
            #pragma unroll
            for(int j=0;j<8;j++) acc[j] = fmaf(ds[q], bf2f(vs[q][j]), acc[j]);
        }
    }
    for(; e+2<=e1; e+=2){
        int i = csr[e + half];
        u16x8 v = X8[(size_t)i*32 + l];
        float d = dinv[i];
        #pragma unroll
        for(int j=0;j<8;j++) acc[j] = fmaf(d, bf2f(v[j]), acc[j]);
    }
    if(e<e1){
        int i = csr[e];
        u16x8 v = X8[(size_t)i*32 + l];
        float d = (half==0)? dinv[i] : 0.f;
        #pragma unroll
        for(int j=0;j<8;j++) acc[j] = fmaf(d, bf2f(v[j]), acc[j]);
    }
    #pragma unroll
    for(int j=0;j<8;j++) acc[j] += __shfl_xor(acc[j], 32, 64);
    if(half==0){
        u16x8 o;
        #pragma unroll
        for(int j=0;j<8;j++) o[j] = f2bf(dn*acc[j]);
        reinterpret_cast<u16x8*>(yb)[(size_t)n*32 + l] = o;
    }
}

// epilogue for 16-row tiles. MODE: 0=INPUT (h0b=xb=o), 1=CONV (xb += 0.9o+0.1h0),
// 2=LAST (fout = xb + 0.9o + 0.1h0, fp32)
template<int MODE>
__device__ __forceinline__ void epilogue16(f32x4 (&acc)[4],
    const float* __restrict__ bp, const float* __restrict__ gp, const float* __restrict__ bep,
    ushort* __restrict__ h0b, ushort* __restrict__ xb, float* __restrict__ fout,
    int row0, int wc, int lr, int hi, int N,
    float (*sm1)[4], float (*sm2)[4])
{
    float bcv[4], gcv[4], bev[4];
    #pragma unroll
    for(int nf=0;nf<4;nf++){
        int col = wc*64 + nf*16 + lr;
        bcv[nf]=bp[col]; gcv[nf]=gp[col]; bev[nf]=bep[col];
    }
    #pragma unroll
    for(int r=0;r<4;r++){
        float ls1=0.f, ls2=0.f;
        #pragma unroll
        for(int nf=0;nf<4;nf++){
            float t = gelu_tanh(acc[nf][r] + bcv[nf]);
            acc[nf][r] = t;
            ls1 += t; ls2 += t*t;
        }
        #pragma unroll
        for(int off=1; off<16; off<<=1){
            ls1 += __shfl_xor(ls1, off, 64);
            ls2 += __shfl_xor(ls2, off, 64);
        }
        if(lr==0){
            int row = hi*4 + r;
            sm1[row][wc]=ls1; sm2[row][wc]=ls2;
        }
    }
    __syncthreads();
    #pragma unroll
    for(int r=0;r<4;r++){
        int row = hi*4 + r;
        int grow = row0 + row;
        if(grow >= N) continue;
        float S1 = sm1[row][0]+sm1[row][1]+sm1[row][2]+sm1[row][3];
        float S2 = sm2[row][0]+sm2[row][1]+sm2[row][2]+sm2[row][3];
        float mu = S1*(1.0f/256.0f);
        float var = fmaxf(S2*(1.0f/256.0f) - mu*mu, 0.0f);
        float rs = rsqrtf(var + 1e-5f);
        #pragma unroll
        for(int nf=0;nf<4;nf++){
            int col = wc*64 + nf*16 + lr;
            size_t idx = (size_t)grow*HID + col;
            float o = (acc[nf][r]-mu)*rs*gcv[nf] + bev[nf];
            if(MODE==0){
                ushort ob = f2bf(o);
                h0b[idx] = ob;
                xb[idx] = ob;
            }else{
                float xc = bf2f(xb[idx]) + 0.9f*o + 0.1f*bf2f(h0b[idx]);
                if(MODE==1) xb[idx] = f2bf(xc);
                else        fout[idx] = xc;
            }
        }
    }
}

// input block: 16-row tiles, reads fp32 X[N][128] directly, converts fragments in-reg
__global__ __launch_bounds__(256) void k_gemm_in(const float* __restrict__ X,
    const ushort* __restrict__ Wb,
    const float* __restrict__ bp, const float* __restrict__ gp, const float* __restrict__ bep,
    ushort* __restrict__ h0b, ushort* __restrict__ xb, int N)
{
    const int lane = threadIdx.x & 63;
    const int wc = threadIdx.x >> 6;
    const int lr = lane & 15;
    const int hi = lane >> 4;
    const int row0 = blockIdx.x*16;
    __shared__ float sm1[16][4];
    __shared__ float sm2[16][4];

    f32x4 acc[4];
    #pragma unroll
    for(int n=0;n<4;n++){ acc[n].x=0.f; acc[n].y=0.f; acc[n].z=0.f; acc[n].w=0.f; }

    int r0 = row0 + lr; if(r0 >= N) r0 = N-1;
    const float* xp0 = X + (size_t)r0*128 + hi*8;
    const ushort* bpp = Wb + (wc*64 + lr)*32 + hi*8;

    #pragma unroll
    for(int kb=0; kb<4; kb++){
        float4 p0a = *reinterpret_cast<const float4*>(xp0 + kb*32);
        float4 p0b = *reinterpret_cast<const float4*>(xp0 + kb*32 + 4);
        s16x8 a0;
        a0[0]=(short)f2bf(p0a.x); a0[1]=(short)f2bf(p0a.y); a0[2]=(short)f2bf(p0a.z); a0[3]=(short)f2bf(p0a.w);
        a0[4]=(short)f2bf(p0b.x); a0[5]=(short)f2bf(p0b.y); a0[6]=(short)f2bf(p0b.z); a0[7]=(short)f2bf(p0b.w);
        #pragma unroll
        for(int nf=0;nf<4;nf++){
            s16x8 b = *reinterpret_cast<const s16x8*>(bpp + kb*8192 + nf*512);
            acc[nf] = __builtin_amdgcn_mfma_f32_16x16x32_bf16(a0, b, acc[nf], 0,0,0);
        }
    }
    epilogue16<0>(acc, bp, gp, bep, h0b, xb, nullptr, row0, wc, lr, hi, N, sm1, sm2);
}

// conv GEMM: 16-row tiles, A = yb (aggregated bf16), fused bias/gelu/LN/blend
template<int MODE>
__global__ __launch_bounds__(256) void k_gemm_fused(const ushort* __restrict__ A,
    const ushort* __restrict__ Wb,
    const float* __restrict__ bp, const float* __restrict__ gp, const float* __restrict__ bep,
    ushort* __restrict__ h0b, ushort* __restrict__ xb, float* __restrict__ fout, int N)
{
    const int lane = threadIdx.x & 63;
    const int wc = threadIdx.x >> 6;
    const int lr = lane & 15;
    const int hi = lane >> 4;
    const int row0 = blockIdx.x*16;
    __shared__ float sm1[16][4];
    __shared__ float sm2[16][4];

    f32x4 acc[4];
    #pragma unroll
    for(int n=0;n<4;n++){ acc[n].x=0.f; acc[n].y=0.f; acc[n].z=0.f; acc[n].w=0.f; }

    int r0 = row0 + lr; if(r0 >= N) r0 = N-1;
    const ushort* ap0 = A + (size_t)r0*256 + hi*8;
    const ushort* bpp = Wb + (wc*64 + lr)*32 + hi*8;

    s16x8 a0[2], bb[2][4];
    a0[0] = *reinterpret_cast<const s16x8*>(ap0);
    #pragma unroll
    for(int nf=0;nf<4;nf++) bb[0][nf] = *reinterpret_cast<const s16x8*>(bpp + nf*512);

    #pragma unroll
    for(int kb=0; kb<8; kb++){
        const int cur = kb&1, nxt = cur^1;
        if(kb < 7){
            a0[nxt] = *reinterpret_cast<const s16x8*>(ap0 + (kb+1)*32);
            #pragma unroll
            for(int nf=0;nf<4;nf++)
                bb[nxt][nf] = *reinterpret_cast<const s16x8*>(bpp + (kb+1)*8192 + nf*512);
        }
        #pragma unroll
        for(int nf=0;nf<4;nf++)
            acc[nf] = __builtin_amdgcn_mfma_f32_16x16x32_bf16(a0[cur], bb[cur][nf], acc[nf], 0,0,0);
    }
    epilogue16<MODE>(acc, bp, gp, bep, h0b, xb, fout, row0, wc, lr, hi, N, sm1, sm2);
}

extern "C" void kernel_launch(void* const* d_in, const int* in_sizes, int n_in,
                              void* d_out, int out_size, void* d_ws, size_t ws_size,
                              hipStream_t stream){
    const float* x     = (const float*)d_in[0];
    const int*   ei    = (const int*)d_in[1];
    const float* W_in  = (const float*)d_in[2];
    const float* b_in  = (const float*)d_in[3];
    const float* g_in  = (const float*)d_in[4];
    const float* be_in = (const float*)d_in[5];
    const float* Wc    = (const float*)d_in[6];
    const float* bc    = (const float*)d_in[7];
    const float* gc    = (const float*)d_in[8];
    const float* bec   = (const float*)d_in[9];
    const int N = in_sizes[0]/128;
    const int E = in_sizes[1]/2;
    const int* src = ei;
    const int* dst = ei + E;
    float* fout = (float*)d_out;
    const int B = (N+1023)/1024;

    char* w = (char*)d_ws;
    ushort* xb   = (ushort*)w; w += (size_t)N*HID*2;
    ushort* yb   = (ushort*)w; w += (size_t)N*HID*2;
    ushort* h0b  = (ushort*)w; w += (size_t)N*HID*2;
    ushort* wbin = (ushort*)w; w += (size_t)128*256*2;
    ushort* wbc  = (ushort*)w; w += (size_t)6*65536*2;
    float* dinv  = (float*)w;  w += (size_t)N*4;
    int* cnt     = (int*)w;    w += (size_t)N*4;
    int* cursor  = (int*)w;    w += (size_t)N*4;
    int* csr     = (int*)w;    w += (size_t)E*4;
    int* indptr  = (int*)w;    w += (size_t)(N+1)*4;
    int* tsum    = (int*)w;    w += (size_t)B*256*4;
    int* bsum    = (int*)w;    w += (size_t)B*4;

    k_zero<<<(N+255)/256,256,0,stream>>>(cnt, N);
    k_cvt_count<<<CVTB + (E+255)/256,256,0,stream>>>(W_in, Wc, wbin, wbc, dst, cnt, E);
    k_scan1<<<B,256,0,stream>>>(cnt, tsum, bsum, N);
    k_scan3<<<B,256,0,stream>>>(cnt, tsum, bsum, indptr, cursor, dinv, N, B);
    k_fill<<<(E+255)/256,256,0,stream>>>(src,dst,cursor,csr,E);

    const int GB = (N+15)/16;
    k_gemm_in<<<GB,256,0,stream>>>(x, wbin, b_in, g_in, be_in, h0b, xb, N);
    for(int l=0;l<6;l++){
        k_agg<<<(N+3)/4,256,0,stream>>>(xb, indptr, csr, dinv, yb, N);
        if(l<5)
            k_gemm_fused<1><<<GB,256,0,stream>>>(yb, wbc+(size_t)l*65536,
                bc+(size_t)l*HID, gc+(size_t)l*HID, bec+(size_t)l*HID,
                h0b, xb, nullptr, N);
        else
            k_gemm_fused<2><<<GB,256,0,stream>>>(yb, wbc+(size_t)l*65536,
                bc+(size_t)l*HID, gc+(size_t)l*HID, bec+(size_t)l*HID,
                h0b, xb, fout, N);
    }
}

// Round 16
// 324.586 us; speedup vs baseline: 1.0693x; 1.0054x over previous
//
#include <hip/hip_runtime.h>
#include <hip/hip_bf16.h>
#include <math.h>

#define HID 256
typedef __attribute__((ext_vector_type(8))) short s16x8;
typedef __attribute__((ext_vector_type(8))) ushort u16x8;
typedef __attribute__((ext_vector_type(4))) float f32x4;

__device__ __forceinline__ ushort f2bf(float f){
    uint u = __float_as_uint(f);
    u += 0x7FFF + ((u>>16)&1);
    return (ushort)(u>>16);
}
__device__ __forceinline__ float bf2f(ushort b){
    return __uint_as_float(((uint)b)<<16);
}

// gelu tanh-approx, tanh via fast exp: tanh(u) = 1 - 2/(1+exp(2u))
__device__ __forceinline__ float gelu_tanh(float x){
    float u = 0.7978845608028654f*(x + 0.044715f*x*x*x);
    float t = 1.0f - 2.0f/(1.0f + __expf(2.0f*u));
    return 0.5f*x*(1.0f+t);
}

// dispatch 1: zero cnt (blocks < ZB) + weight convert (rest). Both independent.
__global__ void k_zero_cvt(int* __restrict__ cnt, int N, int ZB,
    const float* __restrict__ Win, const float* __restrict__ Wc,
    ushort* __restrict__ wbin, ushort* __restrict__ wbc){
    int b = blockIdx.x;
    if(b < ZB){
        int i = b*256 + threadIdx.x;
        if(i<N) cnt[i]=0;
    }else{
        int i = (b-ZB)*256 + threadIdx.x;
        if(i < 32768){
            int k = i >> 8, n = i & 255;
            int kb = k>>5, hi=(k>>3)&3, ii=k&7;
            wbin[((kb*256+n)*4+hi)*8 + ii] = f2bf(Win[i]);
        }else if(i < 32768 + 6*65536){
            int j = i - 32768;
            int l = j >> 16;
            int k = (j>>8)&255, n = j&255;
            int kb = k>>5, hi=(k>>3)&3, ii=k&7;
            wbc[l*65536 + ((kb*256+n)*4+hi)*8 + ii] = f2bf(Wc[j]);
        }
    }
}

__global__ void k_count(const int* __restrict__ dst, int* __restrict__ cnt, int E){
    int e = blockIdx.x*blockDim.x + threadIdx.x;
    if(e<E) atomicAdd(&cnt[dst[e]], 1);
}

__global__ __launch_bounds__(256) void k_scan1(const int* __restrict__ cnt,
    int* __restrict__ tsum, int* __restrict__ bsum, int N){
    __shared__ int sm[256];
    int t = threadIdx.x, b = blockIdx.x;
    int base = b*1024 + t*4;
    int c0=0,c1=0,c2=0,c3=0;
    if(base+3 < N){
        int4 c = *reinterpret_cast<const int4*>(&cnt[base]);
        c0=c.x; c1=c.y; c2=c.z; c3=c.w;
    }else{
        if(base  <N) c0=cnt[base];
        if(base+1<N) c1=cnt[base+1];
        if(base+2<N) c2=cnt[base+2];
        if(base+3<N) c3=cnt[base+3];
    }
    int s = c0+c1+c2+c3;
    sm[t]=s; __syncthreads();
    for(int off=1; off<256; off<<=1){
        int v = sm[t];
        int a = (t>=off)? sm[t-off] : 0;
        __syncthreads();
        sm[t] = v+a;
        __syncthreads();
    }
    tsum[b*256+t] = sm[t]-s;
    if(t==255) bsum[b] = sm[255];
}

// scan3: each block sums bsum[0..b-1] itself (B<=20), writes indptr/cursor/dinv
__global__ __launch_bounds__(256) void k_scan3(const int* __restrict__ cnt,
    const int* __restrict__ tsum, const int* __restrict__ bsum,
    int* __restrict__ indptr, int* __restrict__ cursor, float* __restrict__ dinv,
    int N, int B){
    __shared__ int sboff;
    int t = threadIdx.x, b = blockIdx.x;
    if(t==0){
        int run=0, tot=0;
        for(int i=0;i<B;i++){ int v=bsum[i]; if(i<b) run+=v; tot+=v; }
        sboff=run;
        if(b==0) indptr[N]=tot;
    }
    __syncthreads();
    int base = b*1024 + t*4;
    int run = sboff + tsum[b*256+t];
    #pragma unroll
    for(int i=0;i<4;i++){
        int idx = base+i;
        if(idx<N){
            int c = cnt[idx];
            indptr[idx]=run; cursor[idx]=run;
            dinv[idx] = rsqrtf((float)(c+1));
            run += c;
        }
    }
}

// pair-gather: 2 edges per wave-instruction (lane<32 / lane>=32 halves).
// yb[n] = bf16( dinv[n] * (dinv[n]*x[n] + sum_e dinv[src]*x[src]) )
__global__ __launch_bounds__(256) void k_agg(const ushort* __restrict__ xb,
    const int* __restrict__ indptr, const int* __restrict__ csr,
    const float* __restrict__ dinv, ushort* __restrict__ yb, int N)
{
    int wave = threadIdx.x>>6, lane = threadIdx.x&63;
    int n = blockIdx.x*4 + wave;
    if(n>=N) return;
    const u16x8* X8 = reinterpret_cast<const u16x8*>(xb);
    const int half = lane >> 5;
    const int l = lane & 31;
    float dn = dinv[n];
    float acc[8];
    {   // self loop: half 0 carries it with weight dn (outer dn applied at store)
        u16x8 v = X8[(size_t)n*32 + l];
        float w0 = (half==0)? dn : 0.f;
        #pragma unroll
        for(int j=0;j<8;j++) acc[j] = w0 * bf2f(v[j]);
    }
    int e0 = indptr[n], e1 = indptr[n+1];
    int e = e0;
    for(; e+8<=e1; e+=8){
        int is[4];
        #pragma unroll
        for(int q=0;q<4;q++) is[q] = csr[e + q*2 + half];
        u16x8 vs[4];
        #pragma unroll
        for(int q=0;q<4;q++) vs[q] = X8[(size_t)is[q]*32 + l];
        float ds[4];
        #pragma unroll
        for(int q=0;q<4;q++) ds[q] = dinv[is[q]];
        #pragma unroll
        for(int q=0;q<4;q++){
            #pragma unroll
            for(int j=0;j<8;j++) acc[j] = fmaf(ds[q], bf2f(vs[q][j]), acc[j]);
        }
    }
    for(; e+2<=e1; e+=2){
        int i = csr[e + half];
        u16x8 v = X8[(size_t)i*32 + l];
        float d = dinv[i];
        #pragma unroll
        for(int j=0;j<8;j++) acc[j] = fmaf(d, bf2f(v[j]), acc[j]);
    }
    if(e<e1){
        int i = csr[e];
        u16x8 v = X8[(size_t)i*32 + l];
        float d = (half==0)? dinv[i] : 0.f;
        #pragma unroll
        for(int j=0;j<8;j++) acc[j] = fmaf(d, bf2f(v[j]), acc[j]);
    }
    #pragma unroll
    for(int j=0;j<8;j++) acc[j] += __shfl_xor(acc[j], 32, 64);
    if(half==0){
        u16x8 o;
        #pragma unroll
        for(int j=0;j<8;j++) o[j] = f2bf(dn*acc[j]);
        reinterpret_cast<u16x8*>(yb)[(size_t)n*32 + l] = o;
    }
}

// epilogue for 16-row tiles. MODE: 0=INPUT (h0b=xb=o), 1=CONV (xb += 0.9o+0.1h0),
// 2=LAST (fout = xb + 0.9o + 0.1h0, fp32)
template<int MODE>
__device__ __forceinline__ void epilogue16(f32x4 (&acc)[4],
    const float* __restrict__ bp, const float* __restrict__ gp, const float* __restrict__ bep,
    ushort* __restrict__ h0b, ushort* __restrict__ xb, float* __restrict__ fout,
    int row0, int wc, int lr, int hi, int N,
    float (*sm1)[4], float (*sm2)[4])
{
    float bcv[4], gcv[4], bev[4];
    #pragma unroll
    for(int nf=0;nf<4;nf++){
        int col = wc*64 + nf*16 + lr;
        bcv[nf]=bp[col]; gcv[nf]=gp[col]; bev[nf]=bep[col];
    }
    #pragma unroll
    for(int r=0;r<4;r++){
        float ls1=0.f, ls2=0.f;
        #pragma unroll
        for(int nf=0;nf<4;nf++){
            float t = gelu_tanh(acc[nf][r] + bcv[nf]);
            acc[nf][r] = t;
            ls1 += t; ls2 += t*t;
        }
        #pragma unroll
        for(int off=1; off<16; off<<=1){
            ls1 += __shfl_xor(ls1, off, 64);
            ls2 += __shfl_xor(ls2, off, 64);
        }
        if(lr==0){
            int row = hi*4 + r;
            sm1[row][wc]=ls1; sm2[row][wc]=ls2;
        }
    }
    __syncthreads();
    #pragma unroll
    for(int r=0;r<4;r++){
        int row = hi*4 + r;
        int grow = row0 + row;
        if(grow >= N) continue;
        float S1 = sm1[row][0]+sm1[row][1]+sm1[row][2]+sm1[row][3];
        float S2 = sm2[row][0]+sm2[row][1]+sm2[row][2]+sm2[row][3];
        float mu = S1*(1.0f/256.0f);
        float var = fmaxf(S2*(1.0f/256.0f) - mu*mu, 0.0f);
        float rs = rsqrtf(var + 1e-5f);
        #pragma unroll
        for(int nf=0;nf<4;nf++){
            int col = wc*64 + nf*16 + lr;
            size_t idx = (size_t)grow*HID + col;
            float o = (acc[nf][r]-mu)*rs*gcv[nf] + bev[nf];
            if(MODE==0){
                ushort ob = f2bf(o);
                h0b[idx] = ob;
                xb[idx] = ob;
            }else{
                float xc = bf2f(xb[idx]) + 0.9f*o + 0.1f*bf2f(h0b[idx]);
                if(MODE==1) xb[idx] = f2bf(xc);
                else        fout[idx] = xc;
            }
        }
    }
}

// merged dispatch: blocks < FB do CSR fill; rest do the input GEMM (independent work)
__global__ __launch_bounds__(256) void k_fill_gemm_in(
    const int* __restrict__ src, const int* __restrict__ dst,
    int* __restrict__ cursor, int* __restrict__ csr, int E, int FB,
    const float* __restrict__ X, const ushort* __restrict__ Wb,
    const float* __restrict__ bp, const float* __restrict__ gp, const float* __restrict__ bep,
    ushort* __restrict__ h0b, ushort* __restrict__ xb, int N)
{
    if((int)blockIdx.x < FB){
        int e = blockIdx.x*256 + threadIdx.x;
        if(e<E){
            int pos = atomicAdd(&cursor[dst[e]], 1);
            csr[pos] = src[e];
        }
        return;
    }
    const int gb = blockIdx.x - FB;
    const int lane = threadIdx.x & 63;
    const int wc = threadIdx.x >> 6;
    const int lr = lane & 15;
    const int hi = lane >> 4;
    const int row0 = gb*16;
    __shared__ float sm1[16][4];
    __shared__ float sm2[16][4];

    f32x4 acc[4];
    #pragma unroll
    for(int n=0;n<4;n++){ acc[n].x=0.f; acc[n].y=0.f; acc[n].z=0.f; acc[n].w=0.f; }

    int r0 = row0 + lr; if(r0 >= N) r0 = N-1;
    const float* xp0 = X + (size_t)r0*128 + hi*8;
    const ushort* bpp = Wb + (wc*64 + lr)*32 + hi*8;

    #pragma unroll
    for(int kb=0; kb<4; kb++){
        float4 p0a = *reinterpret_cast<const float4*>(xp0 + kb*32);
        float4 p0b = *reinterpret_cast<const float4*>(xp0 + kb*32 + 4);
        s16x8 a0;
        a0[0]=(short)f2bf(p0a.x); a0[1]=(short)f2bf(p0a.y); a0[2]=(short)f2bf(p0a.z); a0[3]=(short)f2bf(p0a.w);
        a0[4]=(short)f2bf(p0b.x); a0[5]=(short)f2bf(p0b.y); a0[6]=(short)f2bf(p0b.z); a0[7]=(short)f2bf(p0b.w);
        #pragma unroll
        for(int nf=0;nf<4;nf++){
            s16x8 b = *reinterpret_cast<const s16x8*>(bpp + kb*8192 + nf*512);
            acc[nf] = __builtin_amdgcn_mfma_f32_16x16x32_bf16(a0, b, acc[nf], 0,0,0);
        }
    }
    epilogue16<0>(acc, bp, gp, bep, h0b, xb, nullptr, row0, wc, lr, hi, N, sm1, sm2);
}

// conv GEMM: 16-row tiles, A = yb (aggregated bf16), fused bias/gelu/LN/blend
template<int MODE>
__global__ __launch_bounds__(256) void k_gemm_fused(const ushort* __restrict__ A,
    const ushort* __restrict__ Wb,
    const float* __restrict__ bp, const float* __restrict__ gp, const float* __restrict__ bep,
    ushort* __restrict__ h0b, ushort* __restrict__ xb, float* __restrict__ fout, int N)
{
    const int lane = threadIdx.x & 63;
    const int wc = threadIdx.x >> 6;
    const int lr = lane & 15;
    const int hi = lane >> 4;
    const int row0 = blockIdx.x*16;
    __shared__ float sm1[16][4];
    __shared__ float sm2[16][4];

    f32x4 acc[4];
    #pragma unroll
    for(int n=0;n<4;n++){ acc[n].x=0.f; acc[n].y=0.f; acc[n].z=0.f; acc[n].w=0.f; }

    int r0 = row0 + lr; if(r0 >= N) r0 = N-1;
    const ushort* ap0 = A + (size_t)r0*256 + hi*8;
    const ushort* bpp = Wb + (wc*64 + lr)*32 + hi*8;

    s16x8 a0[2], bb[2][4];
    a0[0] = *reinterpret_cast<const s16x8*>(ap0);
    #pragma unroll
    for(int nf=0;nf<4;nf++) bb[0][nf] = *reinterpret_cast<const s16x8*>(bpp + nf*512);

    #pragma unroll
    for(int kb=0; kb<8; kb++){
        const int cur = kb&1, nxt = cur^1;
        if(kb < 7){
            a0[nxt] = *reinterpret_cast<const s16x8*>(ap0 + (kb+1)*32);
            #pragma unroll
            for(int nf=0;nf<4;nf++)
                bb[nxt][nf] = *reinterpret_cast<const s16x8*>(bpp + (kb+1)*8192 + nf*512);
        }
        #pragma unroll
        for(int nf=0;nf<4;nf++)
            acc[nf] = __builtin_amdgcn_mfma_f32_16x16x32_bf16(a0[cur], bb[cur][nf], acc[nf], 0,0,0);
    }
    epilogue16<MODE>(acc, bp, gp, bep, h0b, xb, fout, row0, wc, lr, hi, N, sm1, sm2);
}

extern "C" void kernel_launch(void* const* d_in, const int* in_sizes, int n_in,
                              void* d_out, int out_size, void* d_ws, size_t ws_size,
                              hipStream_t stream){
    const float* x     = (const float*)d_in[0];
    const int*   ei    = (const int*)d_in[1];
    const float* W_in  = (const float*)d_in[2];
    const float* b_in  = (const float*)d_in[3];
    const float* g_in  = (const float*)d_in[4];
    const float* be_in = (const float*)d_in[5];
    const float* Wc    = (const float*)d_in[6];
    const float* bc    = (const float*)d_in[7];
    const float* gc    = (const float*)d_in[8];
    const float* bec   = (const float*)d_in[9];
    const int N = in_sizes[0]/128;
    const int E = in_sizes[1]/2;
    const int* src = ei;
    const int* dst = ei + E;
    float* fout = (float*)d_out;
    const int B = (N+1023)/1024;

    char* w = (char*)d_ws;
    ushort* xb   = (ushort*)w; w += (size_t)N*HID*2;
    ushort* yb   = (ushort*)w; w += (size_t)N*HID*2;
    ushort* h0b  = (ushort*)w; w += (size_t)N*HID*2;
    ushort* wbin = (ushort*)w; w += (size_t)128*256*2;
    ushort* wbc  = (ushort*)w; w += (size_t)6*65536*2;
    float* dinv  = (float*)w;  w += (size_t)N*4;
    int* cnt     = (int*)w;    w += (size_t)N*4;
    int* cursor  = (int*)w;    w += (size_t)N*4;
    int* csr     = (int*)w;    w += (size_t)E*4;
    int* indptr  = (int*)w;    w += (size_t)(N+1)*4;
    int* tsum    = (int*)w;    w += (size_t)B*256*4;
    int* bsum    = (int*)w;    w += (size_t)B*4;

    const int ZB = (N+255)/256;                 // zero blocks
    const int CVB = (32768 + 6*65536 + 255)/256; // convert blocks
    k_zero_cvt<<<ZB+CVB,256,0,stream>>>(cnt, N, ZB, W_in, Wc, wbin, wbc);
    k_count<<<(E+255)/256,256,0,stream>>>(dst, cnt, E);
    k_scan1<<<B,256,0,stream>>>(cnt, tsum, bsum, N);
    k_scan3<<<B,256,0,stream>>>(cnt, tsum, bsum, indptr, cursor, dinv, N, B);

    const int FB = (E+255)/256;
    const int GB = (N+15)/16;
    k_fill_gemm_in<<<FB+GB,256,0,stream>>>(src, dst, cursor, csr, E, FB,
                                           x, wbin, b_in, g_in, be_in, h0b, xb, N);
    for(int l=0;l<6;l++){
        k_agg<<<(N+3)/4,256,0,stream>>>(xb, indptr, csr, dinv, yb, N);
        if(l<5)
            k_gemm_fused<1><<<GB,256,0,stream>>>(yb, wbc+(size_t)l*65536,
                bc+(size_t)l*HID, gc+(size_t)l*HID, bec+(size_t)l*HID,
                h0b, xb, nullptr, N);
        else
            k_gemm_fused<2><<<GB,256,0,stream>>>(yb, wbc+(size_t)l*65536,
                bc+(size_t)l*HID, gc+(size_t)l*HID, bec+(size_t)l*HID,
                h0b, xb, fout, N);
    }
}